// Round 19
// baseline (237.741 us; speedup 1.0000x reference)
//
#include <hip/hip_runtime.h>
#include <cmath>

#define LRELU(e) ((e) > 0.f ? (e) : 0.2f*(e))

typedef __bf16 bf16x8 __attribute__((ext_vector_type(8)));
typedef float  f32x4  __attribute__((ext_vector_type(4)));

__device__ __forceinline__ float bflo(unsigned u) { return __uint_as_float(u << 16); }
__device__ __forceinline__ float bfhi(unsigned u) { return __uint_as_float(u & 0xffff0000u); }
__device__ __forceinline__ unsigned packbf(float a, float b) {
  __bf16 x = (__bf16)a, y = (__bf16)b;
  unsigned short ux = *(unsigned short*)&x, uy = *(unsigned short*)&y;
  return ((unsigned)uy << 16) | ux;
}

// swizzled LDS element offset for [row][32] bf16 tiles (BK=32)
#define SWZ32(row, q) ((row)*32 + (((q) ^ (((row)>>1)&3))*8))

#define LGKM0() asm volatile("s_waitcnt lgkmcnt(0)" ::: "memory")
#define VM0()   asm volatile("s_waitcnt vmcnt(0)"   ::: "memory")
#define BAR()   __builtin_amdgcn_s_barrier()

// async global->LDS, 16B per lane; lds base must be wave-uniform
__device__ __forceinline__ void gload_lds16(const void* g, void* l) {
  __builtin_amdgcn_global_load_lds((const __attribute__((address_space(1))) void*)g,
                                   (__attribute__((address_space(3))) void*)l, 16, 0, 0);
}

// ---------------- prep: hist + W1/W2 transpose-to-bf16 (one dispatch) --------
__global__ void k_prep(const int* __restrict__ dst, int* __restrict__ deg, int E,
                       const float* __restrict__ W1, __bf16* __restrict__ W1T,
                       const float* __restrict__ W2, __bf16* __restrict__ W2T) {
  int idx = blockIdx.x*blockDim.x + threadIdx.x;
  if (idx < E) atomicAdd(&deg[dst[idx]], 1);
  if (idx < 256*512) {            // W1T[n][k] = W1[k][n]
    int n = idx >> 9, k = idx & 511;
    W1T[idx] = (__bf16)W1[k*256 + n];
  }
  if (idx < 64*256) {             // W2T[n][k] = W2[k][n]
    int n = idx >> 8, k = idx & 255;
    W2T[idx] = (__bf16)W2[k*64 + n];
  }
}

// ---------------- CSR scan ----------------
__global__ __launch_bounds__(1024) void k_scan1(const int* __restrict__ deg,
                        int* __restrict__ row_start, int* __restrict__ bsums, int n) {
  __shared__ int sm[1024];
  int t = threadIdx.x;
  int i = blockIdx.x*1024 + t;
  sm[t] = (i < n) ? deg[i] : 0;
  __syncthreads();
  for (int off = 1; off < 1024; off <<= 1) {
    int v = (t >= off) ? sm[t-off] : 0;
    __syncthreads();
    sm[t] += v;
    __syncthreads();
  }
  if (i < n) row_start[i+1] = sm[t];
  if (t == 1023) bsums[blockIdx.x] = sm[1023];
  if (i == 0) row_start[0] = 0;
}

__global__ __launch_bounds__(1024) void k_scan3(int* __restrict__ row_start,
                        const int* __restrict__ bsums, int n) {
  int base = 0;
  for (int b = 0; b < blockIdx.x; ++b) base += bsums[b];
  int i = blockIdx.x*1024 + threadIdx.x;
  if (i < n) row_start[i+1] += base;
}

__global__ void k_fill(const int* __restrict__ src, const int* __restrict__ dst,
                       const int* __restrict__ row_start, int* __restrict__ cursor,
                       int* __restrict__ csr_src, int E) {
  int e = blockIdx.x*blockDim.x + threadIdx.x;
  if (e < E) {
    int d = dst[e];
    int pos = atomicAdd(&cursor[d], 1);
    csr_src[row_start[d] + pos] = src[e];
  }
}

// ---------------- GEMM1 (bf16 MFMA) + fused lr1, bf16 feat1 out ----------------
// BM=128, BN=256, BK=32, 512 threads (8 waves 2Mx4N, wave tile 64x64 = head wn).
// T3 2-phase: B staged via global_load_lds (double-buffered, pre-swizzled global
// source -> SWZ32 image in linear-dest LDS); A reg-staged (f32->bf16) into
// single-buffered A_sm. Raw barriers; vmcnt(0) ONCE per tile, after compute.
__global__ __launch_bounds__(512) void k_gemm1(const float* __restrict__ x,
                        const __bf16* __restrict__ W1T, __bf16* __restrict__ feat1,
                        const float* __restrict__ al1, const float* __restrict__ ar1,
                        float* __restrict__ el1, float* __restrict__ er1, int M) {
  const int K = 512, Nn = 256;
  __shared__ __bf16 A_sm[128*32];
  __shared__ __bf16 B_sm[2][256*32];
  int tid = threadIdx.x;
  int lane = tid & 63, wid = tid >> 6;
  int wm = wid >> 2, wn = wid & 3;     // 2 x 4 waves; head = wn
  int bm = blockIdx.x * 128;

  int srow = tid >> 2;                 // A stage row 0..127
  int sq   = tid & 3;                  // A stage 16B chunk

  bool aval = (bm + srow) < M;
  const float* xp = x + (size_t)(bm + srow)*K + sq*8;
  int aw = SWZ32(srow, sq);

  // B gload geometry: wave wid covers rows [wid*32, wid*32+32) in 2 issues of 16 rows
  int brow0 = wid*32 + (lane >> 2);          // issue 0 row
  int brow1 = brow0 + 16;                    // issue 1 row
  int bq0 = (lane & 3) ^ ((brow0 >> 1) & 3); // pre-swizzled source chunk
  int bq1 = (lane & 3) ^ ((brow1 >> 1) & 3);
  const __bf16* bsrc0 = W1T + (size_t)brow0*K + bq0*8;
  const __bf16* bsrc1 = W1T + (size_t)brow1*K + bq1*8;
  int bdst0 = (wid*32)*32;                   // wave-uniform LDS element base
  int bdst1 = (wid*32 + 16)*32;

  // prologue: issue B tile0 -> buf0; load A regs tile0; wait; barrier
  gload_lds16(bsrc0, &B_sm[0][bdst0]);
  gload_lds16(bsrc1, &B_sm[0][bdst1]);
  float4 a0 = make_float4(0.f,0.f,0.f,0.f), a1 = a0;
  if (aval) { a0 = *(const float4*)xp; a1 = *(const float4*)(xp + 4); }
  VM0(); BAR();

  f32x4 acc[4][4];
  #pragma unroll
  for (int i = 0; i < 4; ++i)
    #pragma unroll
    for (int j = 0; j < 4; ++j) acc[i][j] = (f32x4){0.f,0.f,0.f,0.f};

  int cur = 0;
  for (int t = 0; t < 16; ++t) {
    int k0 = t*32;
    // stage A (this tile) from regs
    {
      bf16x8 av;
      av[0]=(__bf16)a0.x; av[1]=(__bf16)a0.y; av[2]=(__bf16)a0.z; av[3]=(__bf16)a0.w;
      av[4]=(__bf16)a1.x; av[5]=(__bf16)a1.y; av[6]=(__bf16)a1.z; av[7]=(__bf16)a1.w;
      *(bf16x8*)&A_sm[aw] = av;
    }
    // issue next tile: B via gload_lds, A via reg loads (covered by compute below)
    if (t + 1 < 16) {
      gload_lds16(bsrc0 + k0 + 32, &B_sm[cur^1][bdst0]);
      gload_lds16(bsrc1 + k0 + 32, &B_sm[cur^1][bdst1]);
      if (aval) { a0 = *(const float4*)(xp + k0 + 32); a1 = *(const float4*)(xp + k0 + 36); }
    }
    LGKM0(); BAR();                     // A_sm writes visible to all waves
    // compute on A_sm, B_sm[cur]
    {
      int q = lane >> 4;
      bf16x8 af[4], bfr[4];
      #pragma unroll
      for (int mf = 0; mf < 4; ++mf) {
        int r = wm*64 + mf*16 + (lane & 15);
        af[mf] = *(const bf16x8*)&A_sm[SWZ32(r, q)];
      }
      #pragma unroll
      for (int nf = 0; nf < 4; ++nf) {
        int r = wn*64 + nf*16 + (lane & 15);
        bfr[nf] = *(const bf16x8*)&B_sm[cur][SWZ32(r, q)];
      }
      #pragma unroll
      for (int mf = 0; mf < 4; ++mf)
        #pragma unroll
        for (int nf = 0; nf < 4; ++nf)
          acc[mf][nf] = __builtin_amdgcn_mfma_f32_16x16x32_bf16(af[mf], bfr[nf], acc[mf][nf], 0, 0, 0);
    }
    VM0(); BAR();                       // next tile's B (and A regs) landed; LDS reads done
    cur ^= 1;
  }

  // epilogue: wave's 64 cols = head wn; fused lr1
  float al_r[4], ar_r[4];
  #pragma unroll
  for (int nf = 0; nf < 4; ++nf) {
    int d = nf*16 + (lane & 15);
    al_r[nf] = al1[wn*64 + d];
    ar_r[nf] = ar1[wn*64 + d];
  }
  #pragma unroll
  for (int mf = 0; mf < 4; ++mf) {
    #pragma unroll
    for (int j = 0; j < 4; ++j) {
      int m = bm + wm*64 + mf*16 + (lane>>4)*4 + j;
      float pl = 0.f, pr = 0.f;
      #pragma unroll
      for (int nf = 0; nf < 4; ++nf) {
        float val = acc[mf][nf][j];
        pl = fmaf(val, al_r[nf], pl);
        pr = fmaf(val, ar_r[nf], pr);
        if (m < M) {
          int n = wn*64 + nf*16 + (lane & 15);
          feat1[(size_t)m*Nn + n] = (__bf16)val;
        }
      }
      #pragma unroll
      for (int s = 8; s >= 1; s >>= 1) {
        pl += __shfl_xor(pl, s);
        pr += __shfl_xor(pr, s);
      }
      if ((lane & 15) == 0 && m < M) {
        el1[m*4 + wn] = pl;
        er1[m*4 + wn] = pr;
      }
    }
  }
}

// ---------------- GEMM2 (bf16 MFMA) + fused lr2, bf16 feat2 out ----------------
__global__ __launch_bounds__(256) void k_gemm2(const __bf16* __restrict__ h1,
                        const __bf16* __restrict__ W2T, __bf16* __restrict__ feat2,
                        const float* __restrict__ al2, const float* __restrict__ ar2,
                        float* __restrict__ el2, float* __restrict__ er2, int M) {
  const int K = 256, Nn = 64;
  __shared__ __bf16 A_sm[128][40];
  __shared__ __bf16 B_sm[64][40];
  int tid = threadIdx.x;
  int lane = tid & 63, wid = tid >> 6;
  int bm = blockIdx.x * 128;

  int srow = tid >> 2;
  int scol = (tid & 3) * 8;

  f32x4 acc[2][4];
  #pragma unroll
  for (int i = 0; i < 2; ++i)
    #pragma unroll
    for (int j = 0; j < 4; ++j) acc[i][j] = (f32x4){0.f,0.f,0.f,0.f};

  for (int k0 = 0; k0 < K; k0 += 32) {
    #pragma unroll
    for (int p = 0; p < 2; ++p) {
      int row = p*64 + srow;
      bf16x8 v = (bf16x8){};
      if (bm + row < M) v = *(const bf16x8*)(h1 + (size_t)(bm+row)*K + k0 + scol);
      *(bf16x8*)&A_sm[row][scol] = v;
    }
    *(bf16x8*)&B_sm[srow][scol] = *(const bf16x8*)(W2T + (size_t)srow*K + k0 + scol);
    __syncthreads();
    bf16x8 af[2], bfr[4];
    #pragma unroll
    for (int mf = 0; mf < 2; ++mf)
      af[mf] = *(const bf16x8*)&A_sm[wid*32 + mf*16 + (lane&15)][(lane>>4)*8];
    #pragma unroll
    for (int nf = 0; nf < 4; ++nf)
      bfr[nf] = *(const bf16x8*)&B_sm[nf*16 + (lane&15)][(lane>>4)*8];
    #pragma unroll
    for (int mf = 0; mf < 2; ++mf)
      #pragma unroll
      for (int nf = 0; nf < 4; ++nf)
        acc[mf][nf] = __builtin_amdgcn_mfma_f32_16x16x32_bf16(af[mf], bfr[nf], acc[mf][nf], 0, 0, 0);
    __syncthreads();
  }
  float al_r[4], ar_r[4];
  #pragma unroll
  for (int nf = 0; nf < 4; ++nf) {
    int n = nf*16 + (lane&15);
    al_r[nf] = al2[n];
    ar_r[nf] = ar2[n];
  }
  #pragma unroll
  for (int mf = 0; mf < 2; ++mf) {
    #pragma unroll
    for (int j = 0; j < 4; ++j) {
      int m = bm + wid*32 + mf*16 + (lane>>4)*4 + j;
      float pl = 0.f, pr = 0.f;
      #pragma unroll
      for (int nf = 0; nf < 4; ++nf) {
        float val = acc[mf][nf][j];
        pl = fmaf(val, al_r[nf], pl);
        pr = fmaf(val, ar_r[nf], pr);
        if (m < M) {
          int n = nf*16 + (lane&15);
          feat2[(size_t)m*Nn + n] = (__bf16)val;
        }
      }
      #pragma unroll
      for (int s = 8; s >= 1; s >>= 1) {
        pl += __shfl_xor(pl, s);
        pr += __shfl_xor(pr, s);
      }
      if ((lane & 15) == 0 && m < M) {
        el2[m] = pl;
        er2[m] = pr;
      }
    }
  }
}

// ---------------- layer-1: 1 wave = 1 node = ALL 4 heads ----------------------
__global__ __launch_bounds__(256) void k_agg1(const __bf16* __restrict__ feat1,
                      const float* __restrict__ el, const float* __restrict__ er,
                      const int* __restrict__ row_start, const int* __restrict__ csr_src,
                      const float* __restrict__ b1, __bf16* __restrict__ h1, int Nn) {
  __shared__ float ex_sm[4][131][4];   // [wave][edge slot][head]
  __shared__ int   s_sm[4][132];       // s*256
  int w = threadIdx.x >> 6;
  int v = blockIdx.x*4 + w;
  int lane = threadIdx.x & 63;
  if (v >= Nn) return;
  int r0 = row_start[v], deg = row_start[v+1] - r0;
  int c4 = lane*4;                 // channel base (0..252)
  int hd2 = lane >> 4;             // aggregation head
  if (deg == 0) {
    float o0 = b1[c4], o1 = b1[c4+1], o2 = b1[c4+2], o3 = b1[c4+3];
    o0 = o0 > 0.f ? o0 : expm1f(o0);
    o1 = o1 > 0.f ? o1 : expm1f(o1);
    o2 = o2 > 0.f ? o2 : expm1f(o2);
    o3 = o3 > 0.f ? o3 : expm1f(o3);
    *(uint2*)(h1 + (size_t)v*256 + c4) = make_uint2(packbf(o0,o1), packbf(o2,o3));
    return;
  }
  int islot = lane >> 2;           // 0..15
  int hd = lane & 3;               // softmax head
  float erv = er[v*4 + hd];
  float sum = 0.f;
  float acc0 = 0.f, acc1 = 0.f, acc2 = 0.f, acc3 = 0.f;
  if (deg <= 128) {
    for (int i = islot; i < deg; i += 16) {
      int s = csr_src[r0+i];
      float e = LRELU(el[s*4 + hd] + erv);
      float ex = __expf(e);
      ex_sm[w][i][hd] = ex;
      if (hd == 0) s_sm[w][i] = s*256;
      sum += ex;
    }
    if (lane < 8) ex_sm[w][deg + (lane>>2)][lane&3] = 0.f;
    if (lane < 2) s_sm[w][deg + lane] = 0;
    #pragma unroll
    for (int m = 4; m <= 32; m <<= 1) sum += __shfl_xor(sum, m);
    float inv = 1.f/__shfl(sum, hd2);
    uint2 u = *(const uint2*)(feat1 + (size_t)s_sm[w][0] + c4);
    for (int j = 0; j < deg; ++j) {
      uint2 un = *(const uint2*)(feat1 + (size_t)s_sm[w][j+1] + c4);
      float wj = ex_sm[w][j][hd2];
      acc0 = fmaf(bflo(u.x), wj, acc0);
      acc1 = fmaf(bfhi(u.x), wj, acc1);
      acc2 = fmaf(bflo(u.y), wj, acc2);
      acc3 = fmaf(bfhi(u.y), wj, acc3);
      u = un;
    }
    acc0 *= inv; acc1 *= inv; acc2 *= inv; acc3 *= inv;
  } else {
    for (int i = islot; i < deg; i += 16) {
      int s = csr_src[r0+i];
      float e = LRELU(el[s*4 + hd] + erv);
      sum += __expf(e);
    }
    #pragma unroll
    for (int m = 4; m <= 32; m <<= 1) sum += __shfl_xor(sum, m);
    float inv = 1.f/__shfl(sum, hd2);
    for (int c0 = 0; c0 < deg; c0 += 128) {
      int cnt = min(128, deg - c0);
      for (int i = islot; i < cnt; i += 16) {
        int s = csr_src[r0 + c0 + i];
        float e = LRELU(el[s*4 + hd] + erv);
        ex_sm[w][i][hd] = __expf(e);
        if (hd == 0) s_sm[w][i] = s*256;
      }
      if (lane < 8) ex_sm[w][cnt + (lane>>2)][lane&3] = 0.f;
      if (lane < 2) s_sm[w][cnt + lane] = 0;
      uint2 u = *(const uint2*)(feat1 + (size_t)s_sm[w][0] + c4);
      for (int j = 0; j < cnt; ++j) {
        uint2 un = *(const uint2*)(feat1 + (size_t)s_sm[w][j+1] + c4);
        float wj = ex_sm[w][j][hd2];
        acc0 = fmaf(bflo(u.x), wj, acc0);
        acc1 = fmaf(bfhi(u.x), wj, acc1);
        acc2 = fmaf(bflo(u.y), wj, acc2);
        acc3 = fmaf(bfhi(u.y), wj, acc3);
        u = un;
      }
    }
    acc0 *= inv; acc1 *= inv; acc2 *= inv; acc3 *= inv;
  }
  float o0 = acc0 + b1[c4], o1 = acc1 + b1[c4+1];
  float o2 = acc2 + b1[c4+2], o3 = acc3 + b1[c4+3];
  o0 = o0 > 0.f ? o0 : expm1f(o0);
  o1 = o1 > 0.f ? o1 : expm1f(o1);
  o2 = o2 > 0.f ? o2 : expm1f(o2);
  o3 = o3 > 0.f ? o3 : expm1f(o3);
  *(uint2*)(h1 + (size_t)v*256 + c4) = make_uint2(packbf(o0,o1), packbf(o2,o3));
}

// ---------------- layer-2 softmax + aggregate + bias -> out (f32) ------------
__global__ __launch_bounds__(256) void k_agg2(const __bf16* __restrict__ feat2,
                      const float* __restrict__ el, const float* __restrict__ er,
                      const int* __restrict__ row_start, const int* __restrict__ csr_src,
                      const float* __restrict__ b2, float* __restrict__ out, int Nn) {
  __shared__ float ex_sm[4][136];
  __shared__ int   s_sm[4][136];
  int w = threadIdx.x >> 6;
  int v = blockIdx.x*4 + w;
  int lane = threadIdx.x & 63;
  if (v >= Nn) return;
  int r0 = row_start[v], deg = row_start[v+1] - r0;
  if (deg == 0) {
    out[(size_t)v*64 + lane] = b2[lane];
    return;
  }
  float erv = er[v];
  const unsigned short* f16 = (const unsigned short*)feat2;
  float acc = 0.f;
  float inv = 0.f;
  if (deg <= 128) {
    float sm = 0.f;
    for (int i = lane; i < deg; i += 64) {
      int s = csr_src[r0+i];
      float e = LRELU(el[s] + erv);
      float ex = __expf(e);
      ex_sm[w][i] = ex;
      s_sm[w][i] = s*64;
      sm += ex;
    }
    if (lane < 4) { ex_sm[w][deg+lane] = 0.f; s_sm[w][deg+lane] = 0; }
    #pragma unroll
    for (int m = 32; m >= 1; m >>= 1) sm += __shfl_xor(sm, m);
    inv = 1.f/sm;
    unsigned short u0 = f16[(size_t)(s_sm[w][0] + lane)];
    unsigned short u1 = f16[(size_t)(s_sm[w][1] + lane)];
    for (int j = 0; j < deg; ++j) {
      unsigned short u2 = f16[(size_t)(s_sm[w][j+2] + lane)];
      acc = fmaf(__uint_as_float((unsigned)u0 << 16), ex_sm[w][j], acc);
      u0 = u1; u1 = u2;
    }
  } else {
    float sm = 0.f;
    for (int i = lane; i < deg; i += 64) {
      int s = csr_src[r0+i];
      float e = LRELU(el[s] + erv);
      sm += __expf(e);
    }
    #pragma unroll
    for (int m = 32; m >= 1; m >>= 1) sm += __shfl_xor(sm, m);
    inv = 1.f/sm;
    for (int c0 = 0; c0 < deg; c0 += 128) {
      int cnt = min(128, deg - c0);
      #pragma unroll
      for (int q = 0; q < 2; ++q) {
        int j = q*64 + lane;
        if (j < cnt) {
          int s = csr_src[r0 + c0 + j];
          float e = LRELU(el[s] + erv);
          ex_sm[w][j] = __expf(e);
          s_sm[w][j] = s*64;
        }
      }
      for (int j = 0; j < cnt; ++j) {
        acc = fmaf(__uint_as_float((unsigned)f16[(size_t)(s_sm[w][j] + lane)] << 16),
                   ex_sm[w][j], acc);
      }
    }
  }
  out[(size_t)v*64 + lane] = acc*inv + b2[lane];
}

extern "C" void kernel_launch(void* const* d_in, const int* in_sizes, int n_in,
                              void* d_out, int out_size, void* d_ws, size_t ws_size,
                              hipStream_t stream) {
  const float* x   = (const float*)d_in[0];
  const int*   src = (const int*)d_in[1];
  const int*   dst = (const int*)d_in[2];
  const float* W1  = (const float*)d_in[3];
  const float* al1 = (const float*)d_in[4];
  const float* ar1 = (const float*)d_in[5];
  const float* b1  = (const float*)d_in[6];
  const float* W2  = (const float*)d_in[7];
  const float* al2 = (const float*)d_in[8];
  const float* ar2 = (const float*)d_in[9];
  const float* b2  = (const float*)d_in[10];
  float* out = (float*)d_out;

  const int N = in_sizes[0] / 512;
  const int E = in_sizes[1];

  char* p = (char*)d_ws;
  auto alloc = [&](size_t bytes) {
    char* r = p; p += (bytes + 255) & ~(size_t)255; return r;
  };
  int*   deg      = (int*)alloc((size_t)N*sizeof(int));
  int*   cursor   = (int*)alloc((size_t)N*sizeof(int));
  __bf16* feat1   = (__bf16*)alloc((size_t)N*256*sizeof(__bf16));
  __bf16* h1      = (__bf16*)alloc((size_t)N*256*sizeof(__bf16));
  __bf16* feat2   = (__bf16*)alloc((size_t)N*64*sizeof(__bf16));
  float* el1      = (float*)alloc((size_t)N*4*sizeof(float));
  float* er1      = (float*)alloc((size_t)N*4*sizeof(float));
  float* el2      = (float*)alloc((size_t)N*sizeof(float));
  float* er2      = (float*)alloc((size_t)N*sizeof(float));
  int*   row_start= (int*)alloc((size_t)(N+1)*sizeof(int));
  int*   bsums    = (int*)alloc(64*sizeof(int));
  int*   csr_src  = (int*)alloc((size_t)E*sizeof(int));
  __bf16* w1t     = (__bf16*)alloc((size_t)256*512*sizeof(__bf16));
  __bf16* w2t     = (__bf16*)alloc((size_t)64*256*sizeof(__bf16));

  hipMemsetAsync(deg, 0, (size_t)((char*)cursor - (char*)deg) + (size_t)N*sizeof(int), stream);

  k_prep<<<(E+255)/256, 256, 0, stream>>>(dst, deg, E, W1, w1t, W2, w2t);
  int nb = (N + 1023)/1024;
  k_scan1<<<nb, 1024, 0, stream>>>(deg, row_start, bsums, N);
  k_scan3<<<nb, 1024, 0, stream>>>(row_start, bsums, N);
  k_fill<<<(E+255)/256, 256, 0, stream>>>(src, dst, row_start, cursor, csr_src, E);

  k_gemm1<<<(N+127)/128, 512, 0, stream>>>(x, w1t, feat1, al1, ar1, el1, er1, N);
  k_agg1<<<(N+3)/4, 256, 0, stream>>>(feat1, el1, er1, row_start, csr_src, b1, h1, N);
  k_gemm2<<<(N+127)/128, 256, 0, stream>>>(h1, w2t, feat2, al2, ar2, el2, er2, N);
  k_agg2<<<(N+3)/4, 256, 0, stream>>>(feat2, el2, er2, row_start, csr_src, b2, out, N);
}

// Round 20
// 224.854 us; speedup vs baseline: 1.0573x; 1.0573x over previous
//
#include <hip/hip_runtime.h>
#include <cmath>

#define LRELU(e) ((e) > 0.f ? (e) : 0.2f*(e))

typedef __bf16 bf16x8 __attribute__((ext_vector_type(8)));
typedef float  f32x4  __attribute__((ext_vector_type(4)));

__device__ __forceinline__ float bflo(unsigned u) { return __uint_as_float(u << 16); }
__device__ __forceinline__ float bfhi(unsigned u) { return __uint_as_float(u & 0xffff0000u); }
__device__ __forceinline__ unsigned packbf(float a, float b) {
  __bf16 x = (__bf16)a, y = (__bf16)b;
  unsigned short ux = *(unsigned short*)&x, uy = *(unsigned short*)&y;
  return ((unsigned)uy << 16) | ux;
}

// swizzled LDS element offset for [row][32] bf16 tiles (BK=32)
#define SWZ32(row, q) ((row)*32 + (((q) ^ (((row)>>1)&3))*8))

// ---------------- prep: hist + W1/W2 transpose-to-bf16 (one dispatch) --------
__global__ void k_prep(const int* __restrict__ dst, int* __restrict__ deg, int E,
                       const float* __restrict__ W1, __bf16* __restrict__ W1T,
                       const float* __restrict__ W2, __bf16* __restrict__ W2T) {
  int idx = blockIdx.x*blockDim.x + threadIdx.x;
  if (idx < E) atomicAdd(&deg[dst[idx]], 1);
  if (idx < 256*512) {            // W1T[n][k] = W1[k][n]
    int n = idx >> 9, k = idx & 511;
    W1T[idx] = (__bf16)W1[k*256 + n];
  }
  if (idx < 64*256) {             // W2T[n][k] = W2[k][n]
    int n = idx >> 8, k = idx & 255;
    W2T[idx] = (__bf16)W2[k*64 + n];
  }
}

// ---------------- CSR scan ----------------
__global__ __launch_bounds__(1024) void k_scan1(const int* __restrict__ deg,
                        int* __restrict__ row_start, int* __restrict__ bsums, int n) {
  __shared__ int sm[1024];
  int t = threadIdx.x;
  int i = blockIdx.x*1024 + t;
  sm[t] = (i < n) ? deg[i] : 0;
  __syncthreads();
  for (int off = 1; off < 1024; off <<= 1) {
    int v = (t >= off) ? sm[t-off] : 0;
    __syncthreads();
    sm[t] += v;
    __syncthreads();
  }
  if (i < n) row_start[i+1] = sm[t];
  if (t == 1023) bsums[blockIdx.x] = sm[1023];
  if (i == 0) row_start[0] = 0;
}

// scan3': each block redundantly prefix-sums raw per-block totals (nb <= 64)
__global__ __launch_bounds__(1024) void k_scan3(int* __restrict__ row_start,
                        const int* __restrict__ bsums, int n) {
  int base = 0;
  for (int b = 0; b < blockIdx.x; ++b) base += bsums[b];
  int i = blockIdx.x*1024 + threadIdx.x;
  if (i < n) row_start[i+1] += base;
}

__global__ void k_fill(const int* __restrict__ src, const int* __restrict__ dst,
                       const int* __restrict__ row_start, int* __restrict__ cursor,
                       int* __restrict__ csr_src, int E) {
  int e = blockIdx.x*blockDim.x + threadIdx.x;
  if (e < E) {
    int d = dst[e];
    int pos = atomicAdd(&cursor[d], 1);
    csr_src[row_start[d] + pos] = src[e];
  }
}

// ---------------- GEMM1 (bf16 MFMA) + fused lr1, bf16 feat1 out ----------------
// r14-proven config: BM=128, BN=256, BK=32, 512 threads (8 waves 2Mx4N,
// wave tile 64x64 = one head). Register double-buffered staging + SWZ32 LDS.
__global__ __launch_bounds__(512) void k_gemm1(const float* __restrict__ x,
                        const __bf16* __restrict__ W1T, __bf16* __restrict__ feat1,
                        const float* __restrict__ al1, const float* __restrict__ ar1,
                        float* __restrict__ el1, float* __restrict__ er1, int M) {
  const int K = 512, Nn = 256;
  __shared__ __bf16 A_sm[128*32];
  __shared__ __bf16 B_sm[256*32];
  int tid = threadIdx.x;
  int lane = tid & 63, wid = tid >> 6;
  int wm = wid >> 2, wn = wid & 3;     // 2 x 4 waves; head = wn
  int bm = blockIdx.x * 128;

  int srow = tid >> 2;                 // 0..127
  int sq   = tid & 3;                  // 16B chunk

  bool aval = (bm + srow) < M;
  const float*  xp  = x   + (size_t)(bm + srow)*K + sq*8;
  const __bf16* wp0 = W1T + (size_t)srow*K        + sq*8;
  const __bf16* wp1 = W1T + (size_t)(srow+128)*K  + sq*8;

  int aw  = SWZ32(srow, sq);
  int bw0 = SWZ32(srow, sq);
  int bw1 = SWZ32(srow+128, sq);

  float4 a0 = make_float4(0.f,0.f,0.f,0.f), a1 = make_float4(0.f,0.f,0.f,0.f);
  bf16x8 b0, b1;
  if (aval) { a0 = *(const float4*)xp; a1 = *(const float4*)(xp + 4); }
  b0 = *(const bf16x8*)wp0;
  b1 = *(const bf16x8*)wp1;

  f32x4 acc[4][4];
  #pragma unroll
  for (int i = 0; i < 4; ++i)
    #pragma unroll
    for (int j = 0; j < 4; ++j) acc[i][j] = (f32x4){0.f,0.f,0.f,0.f};

  for (int k0 = 0; k0 < K; k0 += 32) {
    bf16x8 av;
    av[0]=(__bf16)a0.x; av[1]=(__bf16)a0.y; av[2]=(__bf16)a0.z; av[3]=(__bf16)a0.w;
    av[4]=(__bf16)a1.x; av[5]=(__bf16)a1.y; av[6]=(__bf16)a1.z; av[7]=(__bf16)a1.w;
    *(bf16x8*)&A_sm[aw]  = av;
    *(bf16x8*)&B_sm[bw0] = b0;
    *(bf16x8*)&B_sm[bw1] = b1;
    __syncthreads();
    if (k0 + 32 < K) {
      if (aval) { a0 = *(const float4*)(xp + k0 + 32); a1 = *(const float4*)(xp + k0 + 36); }
      b0 = *(const bf16x8*)(wp0 + k0 + 32);
      b1 = *(const bf16x8*)(wp1 + k0 + 32);
    }
    int q = lane >> 4;
    bf16x8 af[4], bfr[4];
    #pragma unroll
    for (int mf = 0; mf < 4; ++mf) {
      int r = wm*64 + mf*16 + (lane & 15);
      af[mf] = *(const bf16x8*)&A_sm[SWZ32(r, q)];
    }
    #pragma unroll
    for (int nf = 0; nf < 4; ++nf) {
      int r = wn*64 + nf*16 + (lane & 15);
      bfr[nf] = *(const bf16x8*)&B_sm[SWZ32(r, q)];
    }
    #pragma unroll
    for (int mf = 0; mf < 4; ++mf)
      #pragma unroll
      for (int nf = 0; nf < 4; ++nf)
        acc[mf][nf] = __builtin_amdgcn_mfma_f32_16x16x32_bf16(af[mf], bfr[nf], acc[mf][nf], 0, 0, 0);
    __syncthreads();
  }
  // epilogue: wave's 64 cols = head wn; fused lr1
  float al_r[4], ar_r[4];
  #pragma unroll
  for (int nf = 0; nf < 4; ++nf) {
    int d = nf*16 + (lane & 15);
    al_r[nf] = al1[wn*64 + d];
    ar_r[nf] = ar1[wn*64 + d];
  }
  #pragma unroll
  for (int mf = 0; mf < 4; ++mf) {
    #pragma unroll
    for (int j = 0; j < 4; ++j) {
      int m = bm + wm*64 + mf*16 + (lane>>4)*4 + j;
      float pl = 0.f, pr = 0.f;
      #pragma unroll
      for (int nf = 0; nf < 4; ++nf) {
        float val = acc[mf][nf][j];
        pl = fmaf(val, al_r[nf], pl);
        pr = fmaf(val, ar_r[nf], pr);
        if (m < M) {
          int n = wn*64 + nf*16 + (lane & 15);
          feat1[(size_t)m*Nn + n] = (__bf16)val;
        }
      }
      #pragma unroll
      for (int s = 8; s >= 1; s >>= 1) {
        pl += __shfl_xor(pl, s);
        pr += __shfl_xor(pr, s);
      }
      if ((lane & 15) == 0 && m < M) {
        el1[m*4 + wn] = pl;
        er1[m*4 + wn] = pr;
      }
    }
  }
}

// ---------------- GEMM2 (bf16 MFMA) + fused lr2, bf16 feat2 out ----------------
__global__ __launch_bounds__(256) void k_gemm2(const __bf16* __restrict__ h1,
                        const __bf16* __restrict__ W2T, __bf16* __restrict__ feat2,
                        const float* __restrict__ al2, const float* __restrict__ ar2,
                        float* __restrict__ el2, float* __restrict__ er2, int M) {
  const int K = 256, Nn = 64;
  __shared__ __bf16 A_sm[128][40];
  __shared__ __bf16 B_sm[64][40];
  int tid = threadIdx.x;
  int lane = tid & 63, wid = tid >> 6;
  int bm = blockIdx.x * 128;

  int srow = tid >> 2;
  int scol = (tid & 3) * 8;

  f32x4 acc[2][4];
  #pragma unroll
  for (int i = 0; i < 2; ++i)
    #pragma unroll
    for (int j = 0; j < 4; ++j) acc[i][j] = (f32x4){0.f,0.f,0.f,0.f};

  for (int k0 = 0; k0 < K; k0 += 32) {
    #pragma unroll
    for (int p = 0; p < 2; ++p) {
      int row = p*64 + srow;
      bf16x8 v = (bf16x8){};
      if (bm + row < M) v = *(const bf16x8*)(h1 + (size_t)(bm+row)*K + k0 + scol);
      *(bf16x8*)&A_sm[row][scol] = v;
    }
    *(bf16x8*)&B_sm[srow][scol] = *(const bf16x8*)(W2T + (size_t)srow*K + k0 + scol);
    __syncthreads();
    bf16x8 af[2], bfr[4];
    #pragma unroll
    for (int mf = 0; mf < 2; ++mf)
      af[mf] = *(const bf16x8*)&A_sm[wid*32 + mf*16 + (lane&15)][(lane>>4)*8];
    #pragma unroll
    for (int nf = 0; nf < 4; ++nf)
      bfr[nf] = *(const bf16x8*)&B_sm[nf*16 + (lane&15)][(lane>>4)*8];
    #pragma unroll
    for (int mf = 0; mf < 2; ++mf)
      #pragma unroll
      for (int nf = 0; nf < 4; ++nf)
        acc[mf][nf] = __builtin_amdgcn_mfma_f32_16x16x32_bf16(af[mf], bfr[nf], acc[mf][nf], 0, 0, 0);
    __syncthreads();
  }
  float al_r[4], ar_r[4];
  #pragma unroll
  for (int nf = 0; nf < 4; ++nf) {
    int n = nf*16 + (lane&15);
    al_r[nf] = al2[n];
    ar_r[nf] = ar2[n];
  }
  #pragma unroll
  for (int mf = 0; mf < 2; ++mf) {
    #pragma unroll
    for (int j = 0; j < 4; ++j) {
      int m = bm + wid*32 + mf*16 + (lane>>4)*4 + j;
      float pl = 0.f, pr = 0.f;
      #pragma unroll
      for (int nf = 0; nf < 4; ++nf) {
        float val = acc[mf][nf][j];
        pl = fmaf(val, al_r[nf], pl);
        pr = fmaf(val, ar_r[nf], pr);
        if (m < M) {
          int n = nf*16 + (lane&15);
          feat2[(size_t)m*Nn + n] = (__bf16)val;
        }
      }
      #pragma unroll
      for (int s = 8; s >= 1; s >>= 1) {
        pl += __shfl_xor(pl, s);
        pr += __shfl_xor(pr, s);
      }
      if ((lane & 15) == 0 && m < M) {
        el2[m] = pl;
        er2[m] = pr;
      }
    }
  }
}

// ---------------- layer-1: 1 wave = 1 node = ALL 4 heads ----------------------
__global__ __launch_bounds__(256) void k_agg1(const __bf16* __restrict__ feat1,
                      const float* __restrict__ el, const float* __restrict__ er,
                      const int* __restrict__ row_start, const int* __restrict__ csr_src,
                      const float* __restrict__ b1, __bf16* __restrict__ h1, int Nn) {
  __shared__ float ex_sm[4][131][4];   // [wave][edge slot][head]
  __shared__ int   s_sm[4][132];       // s*256
  int w = threadIdx.x >> 6;
  int v = blockIdx.x*4 + w;
  int lane = threadIdx.x & 63;
  if (v >= Nn) return;
  int r0 = row_start[v], deg = row_start[v+1] - r0;
  int c4 = lane*4;                 // channel base (0..252)
  int hd2 = lane >> 4;             // aggregation head
  if (deg == 0) {
    float o0 = b1[c4], o1 = b1[c4+1], o2 = b1[c4+2], o3 = b1[c4+3];
    o0 = o0 > 0.f ? o0 : expm1f(o0);
    o1 = o1 > 0.f ? o1 : expm1f(o1);
    o2 = o2 > 0.f ? o2 : expm1f(o2);
    o3 = o3 > 0.f ? o3 : expm1f(o3);
    *(uint2*)(h1 + (size_t)v*256 + c4) = make_uint2(packbf(o0,o1), packbf(o2,o3));
    return;
  }
  int islot = lane >> 2;           // 0..15
  int hd = lane & 3;               // softmax head
  float erv = er[v*4 + hd];
  float sum = 0.f;
  float acc0 = 0.f, acc1 = 0.f, acc2 = 0.f, acc3 = 0.f;
  if (deg <= 128) {
    for (int i = islot; i < deg; i += 16) {
      int s = csr_src[r0+i];
      float e = LRELU(el[s*4 + hd] + erv);
      float ex = __expf(e);
      ex_sm[w][i][hd] = ex;
      if (hd == 0) s_sm[w][i] = s*256;
      sum += ex;
    }
    if (lane < 8) ex_sm[w][deg + (lane>>2)][lane&3] = 0.f;
    if (lane < 2) s_sm[w][deg + lane] = 0;
    #pragma unroll
    for (int m = 4; m <= 32; m <<= 1) sum += __shfl_xor(sum, m);
    float inv = 1.f/__shfl(sum, hd2);
    uint2 u = *(const uint2*)(feat1 + (size_t)s_sm[w][0] + c4);
    for (int j = 0; j < deg; ++j) {
      uint2 un = *(const uint2*)(feat1 + (size_t)s_sm[w][j+1] + c4);
      float wj = ex_sm[w][j][hd2];
      acc0 = fmaf(bflo(u.x), wj, acc0);
      acc1 = fmaf(bfhi(u.x), wj, acc1);
      acc2 = fmaf(bflo(u.y), wj, acc2);
      acc3 = fmaf(bfhi(u.y), wj, acc3);
      u = un;
    }
    acc0 *= inv; acc1 *= inv; acc2 *= inv; acc3 *= inv;
  } else {
    for (int i = islot; i < deg; i += 16) {
      int s = csr_src[r0+i];
      float e = LRELU(el[s*4 + hd] + erv);
      sum += __expf(e);
    }
    #pragma unroll
    for (int m = 4; m <= 32; m <<= 1) sum += __shfl_xor(sum, m);
    float inv = 1.f/__shfl(sum, hd2);
    for (int c0 = 0; c0 < deg; c0 += 128) {
      int cnt = min(128, deg - c0);
      for (int i = islot; i < cnt; i += 16) {
        int s = csr_src[r0 + c0 + i];
        float e = LRELU(el[s*4 + hd] + erv);
        ex_sm[w][i][hd] = __expf(e);
        if (hd == 0) s_sm[w][i] = s*256;
      }
      if (lane < 8) ex_sm[w][cnt + (lane>>2)][lane&3] = 0.f;
      if (lane < 2) s_sm[w][cnt + lane] = 0;
      uint2 u = *(const uint2*)(feat1 + (size_t)s_sm[w][0] + c4);
      for (int j = 0; j < cnt; ++j) {
        uint2 un = *(const uint2*)(feat1 + (size_t)s_sm[w][j+1] + c4);
        float wj = ex_sm[w][j][hd2];
        acc0 = fmaf(bflo(u.x), wj, acc0);
        acc1 = fmaf(bfhi(u.x), wj, acc1);
        acc2 = fmaf(bflo(u.y), wj, acc2);
        acc3 = fmaf(bfhi(u.y), wj, acc3);
        u = un;
      }
    }
    acc0 *= inv; acc1 *= inv; acc2 *= inv; acc3 *= inv;
  }
  float o0 = acc0 + b1[c4], o1 = acc1 + b1[c4+1];
  float o2 = acc2 + b1[c4+2], o3 = acc3 + b1[c4+3];
  o0 = o0 > 0.f ? o0 : expm1f(o0);
  o1 = o1 > 0.f ? o1 : expm1f(o1);
  o2 = o2 > 0.f ? o2 : expm1f(o2);
  o3 = o3 > 0.f ? o3 : expm1f(o3);
  *(uint2*)(h1 + (size_t)v*256 + c4) = make_uint2(packbf(o0,o1), packbf(o2,o3));
}

// ---------------- layer-2 softmax + aggregate + bias -> out (f32) ------------
__global__ __launch_bounds__(256) void k_agg2(const __bf16* __restrict__ feat2,
                      const float* __restrict__ el, const float* __restrict__ er,
                      const int* __restrict__ row_start, const int* __restrict__ csr_src,
                      const float* __restrict__ b2, float* __restrict__ out, int Nn) {
  __shared__ float ex_sm[4][136];
  __shared__ int   s_sm[4][136];
  int w = threadIdx.x >> 6;
  int v = blockIdx.x*4 + w;
  int lane = threadIdx.x & 63;
  if (v >= Nn) return;
  int r0 = row_start[v], deg = row_start[v+1] - r0;
  if (deg == 0) {
    out[(size_t)v*64 + lane] = b2[lane];
    return;
  }
  float erv = er[v];
  const unsigned short* f16 = (const unsigned short*)feat2;
  float acc = 0.f;
  float inv = 0.f;
  if (deg <= 128) {
    float sm = 0.f;
    for (int i = lane; i < deg; i += 64) {
      int s = csr_src[r0+i];
      float e = LRELU(el[s] + erv);
      float ex = __expf(e);
      ex_sm[w][i] = ex;
      s_sm[w][i] = s*64;
      sm += ex;
    }
    if (lane < 4) { ex_sm[w][deg+lane] = 0.f; s_sm[w][deg+lane] = 0; }
    #pragma unroll
    for (int m = 32; m >= 1; m >>= 1) sm += __shfl_xor(sm, m);
    inv = 1.f/sm;
    unsigned short u0 = f16[(size_t)(s_sm[w][0] + lane)];
    unsigned short u1 = f16[(size_t)(s_sm[w][1] + lane)];
    for (int j = 0; j < deg; ++j) {
      unsigned short u2 = f16[(size_t)(s_sm[w][j+2] + lane)];
      acc = fmaf(__uint_as_float((unsigned)u0 << 16), ex_sm[w][j], acc);
      u0 = u1; u1 = u2;
    }
  } else {
    float sm = 0.f;
    for (int i = lane; i < deg; i += 64) {
      int s = csr_src[r0+i];
      float e = LRELU(el[s] + erv);
      sm += __expf(e);
    }
    #pragma unroll
    for (int m = 32; m >= 1; m >>= 1) sm += __shfl_xor(sm, m);
    inv = 1.f/sm;
    for (int c0 = 0; c0 < deg; c0 += 128) {
      int cnt = min(128, deg - c0);
      #pragma unroll
      for (int q = 0; q < 2; ++q) {
        int j = q*64 + lane;
        if (j < cnt) {
          int s = csr_src[r0 + c0 + j];
          float e = LRELU(el[s] + erv);
          ex_sm[w][j] = __expf(e);
          s_sm[w][j] = s*64;
        }
      }
      for (int j = 0; j < cnt; ++j) {
        acc = fmaf(__uint_as_float((unsigned)f16[(size_t)(s_sm[w][j] + lane)] << 16),
                   ex_sm[w][j], acc);
      }
    }
  }
  out[(size_t)v*64 + lane] = acc*inv + b2[lane];
}

extern "C" void kernel_launch(void* const* d_in, const int* in_sizes, int n_in,
                              void* d_out, int out_size, void* d_ws, size_t ws_size,
                              hipStream_t stream) {
  const float* x   = (const float*)d_in[0];
  const int*   src = (const int*)d_in[1];
  const int*   dst = (const int*)d_in[2];
  const float* W1  = (const float*)d_in[3];
  const float* al1 = (const float*)d_in[4];
  const float* ar1 = (const float*)d_in[5];
  const float* b1  = (const float*)d_in[6];
  const float* W2  = (const float*)d_in[7];
  const float* al2 = (const float*)d_in[8];
  const float* ar2 = (const float*)d_in[9];
  const float* b2  = (const float*)d_in[10];
  float* out = (float*)d_out;

  const int N = in_sizes[0] / 512;
  const int E = in_sizes[1];

  char* p = (char*)d_ws;
  auto alloc = [&](size_t bytes) {
    char* r = p; p += (bytes + 255) & ~(size_t)255; return r;
  };
  int*   deg      = (int*)alloc((size_t)N*sizeof(int));
  int*   cursor   = (int*)alloc((size_t)N*sizeof(int));
  __bf16* feat1   = (__bf16*)alloc((size_t)N*256*sizeof(__bf16));
  __bf16* h1      = (__bf16*)alloc((size_t)N*256*sizeof(__bf16));
  __bf16* feat2   = (__bf16*)alloc((size_t)N*64*sizeof(__bf16));
  float* el1      = (float*)alloc((size_t)N*4*sizeof(float));
  float* er1      = (float*)alloc((size_t)N*4*sizeof(float));
  float* el2      = (float*)alloc((size_t)N*sizeof(float));
  float* er2      = (float*)alloc((size_t)N*sizeof(float));
  int*   row_start= (int*)alloc((size_t)(N+1)*sizeof(int));
  int*   bsums    = (int*)alloc(64*sizeof(int));
  int*   csr_src  = (int*)alloc((size_t)E*sizeof(int));
  __bf16* w1t     = (__bf16*)alloc((size_t)256*512*sizeof(__bf16));
  __bf16* w2t     = (__bf16*)alloc((size_t)64*256*sizeof(__bf16));

  hipMemsetAsync(deg, 0, (size_t)((char*)cursor - (char*)deg) + (size_t)N*sizeof(int), stream);

  k_prep<<<(E+255)/256, 256, 0, stream>>>(dst, deg, E, W1, w1t, W2, w2t);
  int nb = (N + 1023)/1024;
  k_scan1<<<nb, 1024, 0, stream>>>(deg, row_start, bsums, N);
  k_scan3<<<nb, 1024, 0, stream>>>(row_start, bsums, N);
  k_fill<<<(E+255)/256, 256, 0, stream>>>(src, dst, row_start, cursor, csr_src, E);

  k_gemm1<<<(N+127)/128, 512, 0, stream>>>(x, w1t, feat1, al1, ar1, el1, er1, N);
  k_agg1<<<(N+3)/4, 256, 0, stream>>>(feat1, el1, er1, row_start, csr_src, b1, h1, N);
  k_gemm2<<<(N+127)/128, 256, 0, stream>>>(h1, w2t, feat2, al2, ar2, el2, er2, N);
  k_agg2<<<(N+3)/4, 256, 0, stream>>>(feat2, el2, er2, row_start, csr_src, b2, out, N);
}